// Round 5
// baseline (143.965 us; speedup 1.0000x reference)
//
#include <hip/hip_runtime.h>

#define DEV static __device__ __forceinline__

typedef __bf16 bf16x8 __attribute__((ext_vector_type(8)));
typedef float  f32x16 __attribute__((ext_vector_type(16)));

// 32x32 MFMA C/D row for reg r, lane-half hi (verified m74/m101)
DEV int rowmap(int r, int hi) { return (r & 3) + 8 * (r >> 2) + 4 * hi; }

// 256B-row tiles (W^T, Q): 16B-block XOR4 swizzle
DEV int swzQ(int row, int col) {
  return row * 256 + (((((col >> 3) ^ (row & 15)) << 3) | (col & 7)) << 1);
}
// 512B-row tile (V^T [128 d][256 k]): XOR5
DEV int swzV(int d, int k) {
  return d * 512 + (((((k >> 3) ^ (d & 31)) << 3) | (k & 7)) << 1);
}

DEV unsigned pack2(float lo, float hi) {
  union { __bf16 h[2]; unsigned u; } x;
  x.h[0] = (__bf16)lo; x.h[1] = (__bf16)hi;
  return x.u;
}
DEV float bflo(unsigned u) { union { unsigned u; float f; } x; x.u = u << 16;        return x.f; }
DEV float bfhi(unsigned u) { union { unsigned u; float f; } x; x.u = u & 0xffff0000u; return x.f; }

// D-layout 16-row slab -> A/B fragment; half-swap via shfl_xor(.,32)+select.
DEV bf16x8 mk_frag(float d0, float d1, float d2, float d3,
                   float d4, float d5, float d6, float d7, int lane) {
  unsigned a0 = pack2(d0, d1), a1 = pack2(d2, d3);
  unsigned b0 = pack2(d4, d5), b1 = pack2(d6, d7);
  unsigned a0s = __shfl_xor(a0, 32), a1s = __shfl_xor(a1, 32);
  unsigned b0s = __shfl_xor(b0, 32), b1s = __shfl_xor(b1, 32);
  bool lo = lane < 32;
  union { unsigned u[4]; bf16x8 v; } r;
  r.u[0] = lo ? a0  : b0s;
  r.u[1] = lo ? a1  : b1s;
  r.u[2] = lo ? a0s : b0;
  r.u[3] = lo ? a1s : b1;
  return r.v;
}

DEV f32x16 fzero() {
  f32x16 z;
  #pragma unroll
  for (int i = 0; i < 16; ++i) z[i] = 0.f;
  return z;
}

// async global->LDS, 16B/lane, wave-uniform LDS base (m97 pattern)
DEV void gld16(const char* g, char* l) {
  __builtin_amdgcn_global_load_lds(
      (const __attribute__((address_space(1))) void*)g,
      (__attribute__((address_space(3))) void*)l, 16, 0, 0);
}

// fallback: stage fp32 W [e][d'] into LDS as swizzled W^T bf16 (1024 thr)
DEV void stage_w32(const float* __restrict__ W, char* dst, int tid) {
  #pragma unroll
  for (int it = 0; it < 16; ++it) {
    int idx = tid + it * 1024;
    int e = idx >> 7, dp = idx & 127;
    *reinterpret_cast<__bf16*>(dst + swzQ(dp, e)) = (__bf16)W[idx];
  }
}

// prep: W fp32 [e][d'] -> bf16 W^T swizzled, packed [Wk|Wq|Wv|Wo] in d_ws
__global__ void prep_wt(const float* __restrict__ Wk, const float* __restrict__ Wq,
                        const float* __restrict__ Wv, const float* __restrict__ Wo,
                        __bf16* __restrict__ wt) {
  int idx = blockIdx.x * 256 + threadIdx.x;   // 0..65535
  const float* W[4] = {Wk, Wq, Wv, Wo};
  int m = idx >> 14, rem = idx & 16383;
  int e = rem >> 7, dp = rem & 127;
  wt[m * 16384 + (swzQ(dp, e) >> 1)] = (__bf16)W[m][rem];
}

template<bool WS>
__global__ __launch_bounds__(1024, 4)
void sapd_fused(const float* __restrict__ S,
                const float* __restrict__ bq, const float* __restrict__ bk,
                const float* __restrict__ bv, const float* __restrict__ bo,
                const float* __restrict__ Wq, const float* __restrict__ Wk,
                const float* __restrict__ Wv, const float* __restrict__ Wo,
                const float* __restrict__ lg, const float* __restrict__ lb,
                const __bf16* __restrict__ wt,
                float* __restrict__ out)
{
  extern __shared__ char smem[];
  char* RA = smem;           // Wk(lo)|Wv(hi) -> V^T [128][256] -> ctx exchange
  char* RB = smem + 65536;   // Wq(lo) -> Q [256][128] -> Wo(lo) + sums(hi)

  const int tid  = threadIdx.x;
  const int lane = tid & 63;
  const int w    = tid >> 6;    // 0..15
  const int p    = w >> 1;      // pair 0..7: owns j rows [32p, 32p+32)
  const int s    = w & 1;       // sub 0/1: d'-half for proj, kt-half for attn
  const int ml   = lane & 31;
  const int hi   = lane >> 5;
  const size_t sbase = (size_t)blockIdx.x * (256 * 128);
  const char* wsc = (const char*)wt;

  // ---- stage Wk->RA.lo, Wq->RB.lo, Wv->RA.hi (96 x 1KB async DMA) ----
  if (WS) {
    #pragma unroll
    for (int jj = 0; jj < 6; ++jj) {
      int c = w + 16 * jj;  // wave-uniform
      char* dst = (c < 32) ? (RA + c * 1024)
                : (c < 64) ? (RB + (c - 32) * 1024)
                           : (RA + 32768 + (c - 64) * 1024);
      gld16(wsc + c * 1024 + lane * 16, dst);
    }
  } else {
    stage_w32(Wk, RA, tid);
    stage_w32(Wq, RB, tid);
    stage_w32(Wv, RA + 32768, tid);
  }

  // ---- S row-fragments for pair rows (both subs identical) ----
  bf16x8 sfrag[8];
  {
    const float* srow = S + sbase + (size_t)(32 * p + ml) * 128;
    #pragma unroll
    for (int kk = 0; kk < 8; ++kk) {
      float4 a = *reinterpret_cast<const float4*>(srow + 16 * kk + 8 * hi);
      float4 b = *reinterpret_cast<const float4*>(srow + 16 * kk + 8 * hi + 4);
      bf16x8 f;
      f[0] = (__bf16)a.x; f[1] = (__bf16)a.y; f[2] = (__bf16)a.z; f[3] = (__bf16)a.w;
      f[4] = (__bf16)b.x; f[5] = (__bf16)b.y; f[6] = (__bf16)b.z; f[7] = (__bf16)b.w;
      sfrag[kk] = f;
    }
  }
  __syncthreads();  // #1: W tiles staged

  // ---- K-proj SWAPPED, full d' (duplicated in pair) -> kfrag regs ----
  bf16x8 kfrag[8];
  {
    f32x16 accK[4];
    #pragma unroll
    for (int t = 0; t < 4; ++t) accK[t] = fzero();
    #pragma unroll
    for (int kk = 0; kk < 8; ++kk) {
      #pragma unroll
      for (int t = 0; t < 4; ++t) {
        bf16x8 wf = *reinterpret_cast<const bf16x8*>(
            RA + swzQ(32 * t + ml, 16 * kk + 8 * hi));
        accK[t] = __builtin_amdgcn_mfma_f32_32x32x16_bf16(wf, sfrag[kk], accK[t], 0, 0, 0);
      }
    }
    #pragma unroll
    for (int t = 0; t < 4; ++t) {
      #pragma unroll
      for (int r = 0; r < 16; ++r) accK[t][r] += bk[32 * t + rowmap(r, hi)];
      kfrag[2 * t]     = mk_frag(accK[t][0], accK[t][1], accK[t][2], accK[t][3],
                                 accK[t][4], accK[t][5], accK[t][6], accK[t][7], lane);
      kfrag[2 * t + 1] = mk_frag(accK[t][8], accK[t][9], accK[t][10], accK[t][11],
                                 accK[t][12], accK[t][13], accK[t][14], accK[t][15], lane);
    }
  }

  // ---- V-proj, own d'-half (t = 2s+tt) ----
  f32x16 accV[2];
  accV[0] = fzero(); accV[1] = fzero();
  #pragma unroll
  for (int kk = 0; kk < 8; ++kk) {
    #pragma unroll
    for (int tt = 0; tt < 2; ++tt) {
      int t = 2 * s + tt;
      bf16x8 wf = *reinterpret_cast<const bf16x8*>(
          RA + 32768 + swzQ(32 * t + ml, 16 * kk + 8 * hi));
      accV[tt] = __builtin_amdgcn_mfma_f32_32x32x16_bf16(sfrag[kk], wf, accV[tt], 0, 0, 0);
    }
  }

  // ---- Q-proj, own d'-half ----
  f32x16 accQ[2];
  accQ[0] = fzero(); accQ[1] = fzero();
  #pragma unroll
  for (int kk = 0; kk < 8; ++kk) {
    #pragma unroll
    for (int tt = 0; tt < 2; ++tt) {
      int t = 2 * s + tt;
      bf16x8 wf = *reinterpret_cast<const bf16x8*>(
          RB + swzQ(32 * t + ml, 16 * kk + 8 * hi));
      accQ[tt] = __builtin_amdgcn_mfma_f32_32x32x16_bf16(sfrag[kk], wf, accQ[tt], 0, 0, 0);
    }
  }
  __syncthreads();  // #2: all W reads done; RA/RB reusable

  // ---- write V^T -> RA, Q rows -> RB ----
  #pragma unroll
  for (int tt = 0; tt < 2; ++tt) {
    int t = 2 * s + tt;
    float bb = bv[32 * t + ml];
    int d = 32 * t + ml;
    #pragma unroll
    for (int q = 0; q < 8; ++q) {
      int k = 32 * p + rowmap(2 * q, hi);  // even; pair (k, k+1)
      *reinterpret_cast<unsigned*>(RA + swzV(d, k)) =
          pack2(accV[tt][2 * q] + bb, accV[tt][2 * q + 1] + bb);
    }
  }
  #pragma unroll
  for (int tt = 0; tt < 2; ++tt) {
    int t = 2 * s + tt;
    float bb = bq[32 * t + ml];
    #pragma unroll
    for (int r = 0; r < 16; ++r)
      *reinterpret_cast<__bf16*>(
          RB + swzQ(32 * p + rowmap(r, hi), 32 * t + ml)) =
          (__bf16)(accQ[tt][r] + bb);
  }
  __syncthreads();  // #3: Q + V^T visible

  // ---- attention, own kt-half (kt = 4s+c): sa -> relu -> ctx^T partial ----
  f32x16 ctx[4];
  #pragma unroll
  for (int m = 0; m < 4; ++m) ctx[m] = fzero();
  const float SC = 0.088388347648318447f;  // 1/sqrt(128)

  #pragma unroll
  for (int c = 0; c < 4; ++c) {
    int kt = 4 * s + c;
    f32x16 sa = fzero();
    __builtin_amdgcn_s_setprio(1);
    #pragma unroll
    for (int kk = 0; kk < 8; ++kk) {
      bf16x8 qf = *reinterpret_cast<const bf16x8*>(
          RB + swzQ(32 * kt + ml, 16 * kk + 8 * hi));
      sa = __builtin_amdgcn_mfma_f32_32x32x16_bf16(qf, kfrag[kk], sa, 0, 0, 0);
    }
    __builtin_amdgcn_s_setprio(0);
    float pv[16];
    #pragma unroll
    for (int r = 0; r < 16; ++r) pv[r] = fmaxf(sa[r] * SC, 0.f);
    bf16x8 pf0 = mk_frag(pv[0], pv[1], pv[2], pv[3], pv[4], pv[5], pv[6], pv[7], lane);
    bf16x8 pf1 = mk_frag(pv[8], pv[9], pv[10], pv[11], pv[12], pv[13], pv[14], pv[15], lane);
    __builtin_amdgcn_s_setprio(1);
    #pragma unroll
    for (int m = 0; m < 4; ++m) {
      bf16x8 vf0 = *reinterpret_cast<const bf16x8*>(
          RA + swzV(32 * m + ml, 32 * kt + 8 * hi));
      ctx[m] = __builtin_amdgcn_mfma_f32_32x32x16_bf16(vf0, pf0, ctx[m], 0, 0, 0);
      bf16x8 vf1 = *reinterpret_cast<const bf16x8*>(
          RA + swzV(32 * m + ml, 32 * kt + 16 + 8 * hi));
      ctx[m] = __builtin_amdgcn_mfma_f32_32x32x16_bf16(vf1, pf1, ctx[m], 0, 0, 0);
    }
    __builtin_amdgcn_s_setprio(0);
  }
  __syncthreads();  // #4: all Q (RB) and V^T (RA) reads done

  // ---- Wo DMA -> RB.lo; pair-wise ctx merge through RA (bf16) ----
  if (WS) {
    #pragma unroll
    for (int jj = 0; jj < 2; ++jj) {
      int c = w + 16 * jj;
      gld16(wsc + 98304 + c * 1024 + lane * 16, RB + c * 1024);
    }
  } else {
    stage_w32(Wo, RB, tid);
  }
  char* XC = RA + p * 8192;  // pair-private exchange region [64 d2][32 j] u32
  if (s == 1) {
    #pragma unroll
    for (int m = 0; m < 4; ++m) {
      #pragma unroll
      for (int q = 0; q < 8; ++q) {
        int d2 = (32 * m + rowmap(2 * q, hi)) >> 1;
        *reinterpret_cast<unsigned*>(XC + d2 * 128 + ml * 4) =
            pack2(ctx[m][2 * q], ctx[m][2 * q + 1]);
      }
    }
  }
  __syncthreads();  // #5: sub1 partials visible; Wo DMA drained
  if (s == 0) {
    #pragma unroll
    for (int m = 0; m < 4; ++m) {
      #pragma unroll
      for (int q = 0; q < 8; ++q) {
        int d2 = (32 * m + rowmap(2 * q, hi)) >> 1;
        unsigned u = *reinterpret_cast<unsigned*>(XC + d2 * 128 + ml * 4);
        ctx[m][2 * q]     += bflo(u);
        ctx[m][2 * q + 1] += bfhi(u);
      }
    }
    #pragma unroll
    for (int m = 0; m < 4; ++m) {
      #pragma unroll
      for (int q = 0; q < 8; ++q) {
        int d2 = (32 * m + rowmap(2 * q, hi)) >> 1;
        *reinterpret_cast<unsigned*>(XC + d2 * 128 + ml * 4) =
            pack2(ctx[m][2 * q], ctx[m][2 * q + 1]);
      }
    }
  }
  __syncthreads();  // #6: merged ctx visible
  if (s == 1) {
    #pragma unroll
    for (int m = 0; m < 4; ++m) {
      #pragma unroll
      for (int q = 0; q < 8; ++q) {
        int d2 = (32 * m + rowmap(2 * q, hi)) >> 1;
        unsigned u = *reinterpret_cast<unsigned*>(XC + d2 * 128 + ml * 4);
        ctx[m][2 * q]     = bflo(u);
        ctx[m][2 * q + 1] = bfhi(u);
      }
    }
  }

  // ---- ctx^T -> A-frags; residual loads (own d'-half) ----
  bf16x8 cf[8];
  #pragma unroll
  for (int m = 0; m < 4; ++m) {
    cf[2 * m]     = mk_frag(ctx[m][0], ctx[m][1], ctx[m][2], ctx[m][3],
                            ctx[m][4], ctx[m][5], ctx[m][6], ctx[m][7], lane);
    cf[2 * m + 1] = mk_frag(ctx[m][8], ctx[m][9], ctx[m][10], ctx[m][11],
                            ctx[m][12], ctx[m][13], ctx[m][14], ctx[m][15], lane);
  }
  float resv[2][16];
  #pragma unroll
  for (int tt = 0; tt < 2; ++tt) {
    #pragma unroll
    for (int r = 0; r < 16; ++r)
      resv[tt][r] = S[sbase + (size_t)(32 * p + rowmap(r, hi)) * 128 +
                      32 * (2 * s + tt) + ml];
  }

  // ---- out-proj, own d'-half ----
  f32x16 oa[2];
  oa[0] = fzero(); oa[1] = fzero();
  #pragma unroll
  for (int kk = 0; kk < 8; ++kk) {
    #pragma unroll
    for (int tt = 0; tt < 2; ++tt) {
      int t = 2 * s + tt;
      bf16x8 wf = *reinterpret_cast<const bf16x8*>(
          RB + swzQ(32 * t + ml, 16 * kk + 8 * hi));
      oa[tt] = __builtin_amdgcn_mfma_f32_32x32x16_bf16(cf[kk], wf, oa[tt], 0, 0, 0);
    }
  }

  // ---- epilogue: +bo, +residual, cross-sub LN reduce, store own half ----
  float gg[2], lbv[2], bov[2];
  #pragma unroll
  for (int tt = 0; tt < 2; ++tt) {
    int t = 2 * s + tt;
    gg[tt]  = lg[32 * t + ml];
    lbv[tt] = lb[32 * t + ml];
    bov[tt] = bo[32 * t + ml];
  }
  float sum[16], ssq[16];
  #pragma unroll
  for (int r = 0; r < 16; ++r) { sum[r] = 0.f; ssq[r] = 0.f; }
  #pragma unroll
  for (int tt = 0; tt < 2; ++tt) {
    #pragma unroll
    for (int r = 0; r < 16; ++r) {
      float x = oa[tt][r] + bov[tt] + resv[tt][r];
      oa[tt][r] = x;
      sum[r] += x;
      ssq[r] += x * x;
    }
  }
  char* SX = RB + 32768;  // sums exchange: [pair][32 row][2 sub] float2
  #pragma unroll
  for (int r = 0; r < 16; ++r) {
    float s_ = sum[r], q_ = ssq[r];
    #pragma unroll
    for (int m = 1; m <= 16; m <<= 1) {
      s_ += __shfl_xor(s_, m);
      q_ += __shfl_xor(q_, m);
    }
    if (ml == 0) {
      float2 v; v.x = s_; v.y = q_;
      *reinterpret_cast<float2*>(SX + p * 512 + rowmap(r, hi) * 16 + s * 8) = v;
    }
  }
  __syncthreads();  // #7: partial sums visible
  #pragma unroll
  for (int r = 0; r < 16; ++r) {
    int row = rowmap(r, hi);
    float2 a = *reinterpret_cast<float2*>(SX + p * 512 + row * 16);
    float2 b = *reinterpret_cast<float2*>(SX + p * 512 + row * 16 + 8);
    float mu = (a.x + b.x) * (1.f / 128.f);
    float var = (a.y + b.y) * (1.f / 128.f) - mu * mu;
    float rs = rsqrtf(var + 1e-5f);
    float* orow = out + sbase + (size_t)(32 * p + row) * 128;
    #pragma unroll
    for (int tt = 0; tt < 2; ++tt)
      orow[32 * (2 * s + tt) + ml] = (oa[tt][r] - mu) * rs * gg[tt] + lbv[tt];
  }
}

extern "C" void kernel_launch(void* const* d_in, const int* in_sizes, int n_in,
                              void* d_out, int out_size, void* d_ws, size_t ws_size,
                              hipStream_t stream) {
  (void)in_sizes; (void)n_in; (void)out_size;
  const float* S  = (const float*)d_in[1];
  const float* Wq = (const float*)d_in[2];
  const float* bq = (const float*)d_in[3];
  const float* Wk = (const float*)d_in[4];
  const float* bk = (const float*)d_in[5];
  const float* Wv = (const float*)d_in[6];
  const float* bv = (const float*)d_in[7];
  const float* Wo = (const float*)d_in[8];
  const float* bo = (const float*)d_in[9];
  const float* lg = (const float*)d_in[10];
  const float* lb = (const float*)d_in[11];
  float* out = (float*)d_out;

  constexpr int SMEM = 131072;  // 128 KiB; 1 block/CU but 16 waves = 4/SIMD
  bool use_ws = (d_ws != nullptr) && (ws_size >= 131072);
  if (use_ws) {
    prep_wt<<<dim3(256), dim3(256), 0, stream>>>(Wk, Wq, Wv, Wo, (__bf16*)d_ws);
    (void)hipFuncSetAttribute(reinterpret_cast<const void*>(&sapd_fused<true>),
                              hipFuncAttributeMaxDynamicSharedMemorySize, SMEM);
    sapd_fused<true><<<dim3(512), dim3(1024), SMEM, stream>>>(
        S, bq, bk, bv, bo, Wq, Wk, Wv, Wo, lg, lb, (const __bf16*)d_ws, out);
  } else {
    (void)hipFuncSetAttribute(reinterpret_cast<const void*>(&sapd_fused<false>),
                              hipFuncAttributeMaxDynamicSharedMemorySize, SMEM);
    sapd_fused<false><<<dim3(512), dim3(1024), SMEM, stream>>>(
        S, bq, bk, bv, bo, Wq, Wk, Wv, Wo, lg, lb, nullptr, out);
  }
}

// Round 6
// 140.516 us; speedup vs baseline: 1.0245x; 1.0245x over previous
//
#include <hip/hip_runtime.h>

#define DEV static __device__ __forceinline__

typedef __bf16 bf16x8 __attribute__((ext_vector_type(8)));
typedef float  f32x16 __attribute__((ext_vector_type(16)));

// 32x32 MFMA C/D row for reg r, lane-half hi (verified m74/m101)
DEV int rowmap(int r, int hi) { return (r & 3) + 8 * (r >> 2) + 4 * hi; }

// 256B-row tiles (W^T, Q): 16B-block XOR4 swizzle
DEV int swzQ(int row, int col) {
  return row * 256 + (((((col >> 3) ^ (row & 15)) << 3) | (col & 7)) << 1);
}
// 512B-row tile (V^T [128 d][256 k]): XOR5
DEV int swzV(int d, int k) {
  return d * 512 + (((((k >> 3) ^ (d & 31)) << 3) | (k & 7)) << 1);
}

DEV unsigned pack2(float lo, float hi) {
  union { __bf16 h[2]; unsigned u; } x;
  x.h[0] = (__bf16)lo; x.h[1] = (__bf16)hi;
  return x.u;
}
DEV float bflo(unsigned u) { union { unsigned u; float f; } x; x.u = u << 16;        return x.f; }
DEV float bfhi(unsigned u) { union { unsigned u; float f; } x; x.u = u & 0xffff0000u; return x.f; }

// D-layout 16-row slab -> A/B fragment; half-swap via shfl_xor(.,32)+select.
DEV bf16x8 mk_frag(float d0, float d1, float d2, float d3,
                   float d4, float d5, float d6, float d7, int lane) {
  unsigned a0 = pack2(d0, d1), a1 = pack2(d2, d3);
  unsigned b0 = pack2(d4, d5), b1 = pack2(d6, d7);
  unsigned a0s = __shfl_xor(a0, 32), a1s = __shfl_xor(a1, 32);
  unsigned b0s = __shfl_xor(b0, 32), b1s = __shfl_xor(b1, 32);
  bool lo = lane < 32;
  union { unsigned u[4]; bf16x8 v; } r;
  r.u[0] = lo ? a0  : b0s;
  r.u[1] = lo ? a1  : b1s;
  r.u[2] = lo ? a0s : b0;
  r.u[3] = lo ? a1s : b1;
  return r.v;
}

DEV f32x16 fzero() {
  f32x16 z;
  #pragma unroll
  for (int i = 0; i < 16; ++i) z[i] = 0.f;
  return z;
}

// async global->LDS, 16B/lane, wave-uniform LDS base (m97 pattern)
DEV void gld16(const char* g, char* l) {
  __builtin_amdgcn_global_load_lds(
      (const __attribute__((address_space(1))) void*)g,
      (__attribute__((address_space(3))) void*)l, 16, 0, 0);
}

// fallback: stage fp32 W [e][d'] into LDS as swizzled W^T bf16 (1024 thr)
DEV void stage_w32(const float* __restrict__ W, char* dst, int tid) {
  #pragma unroll
  for (int it = 0; it < 16; ++it) {
    int idx = tid + it * 1024;
    int e = idx >> 7, dp = idx & 127;
    *reinterpret_cast<__bf16*>(dst + swzQ(dp, e)) = (__bf16)W[idx];
  }
}

// prep: W fp32 [e][d'] -> bf16 W^T swizzled, packed [Wk|Wq|Wv|Wo] in d_ws
__global__ void prep_wt(const float* __restrict__ Wk, const float* __restrict__ Wq,
                        const float* __restrict__ Wv, const float* __restrict__ Wo,
                        __bf16* __restrict__ wt) {
  int idx = blockIdx.x * 256 + threadIdx.x;   // 0..65535
  const float* W[4] = {Wk, Wq, Wv, Wo};
  int m = idx >> 14, rem = idx & 16383;
  int e = rem >> 7, dp = rem & 127;
  wt[m * 16384 + (swzQ(dp, e) >> 1)] = (__bf16)W[m][rem];
}

template<bool WS>
__global__ __launch_bounds__(1024, 1)   // 1 block/CU: 16 waves, VGPR cap 128
void sapd_fused(const float* __restrict__ S,
                const float* __restrict__ bq, const float* __restrict__ bk,
                const float* __restrict__ bv, const float* __restrict__ bo,
                const float* __restrict__ Wq, const float* __restrict__ Wk,
                const float* __restrict__ Wv, const float* __restrict__ Wo,
                const float* __restrict__ lg, const float* __restrict__ lb,
                const __bf16* __restrict__ wt,
                float* __restrict__ out)
{
  extern __shared__ char smem[];
  char* RA = smem;           // Wk(lo)|Wv(hi) -> V^T [128][256] -> ctx exchange
  char* RB = smem + 65536;   // Wq(lo) -> Q [256][128] -> Wo(lo) + sums(hi)

  const int tid  = threadIdx.x;
  const int lane = tid & 63;
  const int w    = tid >> 6;    // 0..15
  const int p    = w >> 1;      // pair 0..7: owns j rows [32p, 32p+32)
  const int s    = w & 1;       // sub 0/1: d'-half for proj, kt-half for attn
  const int ml   = lane & 31;
  const int hi   = lane >> 5;
  const size_t sbase = (size_t)blockIdx.x * (256 * 128);
  const char* wsc = (const char*)wt;

  // ---- stage Wk->RA.lo, Wq->RB.lo, Wv->RA.hi (96 x 1KB async DMA) ----
  if (WS) {
    #pragma unroll
    for (int jj = 0; jj < 6; ++jj) {
      int c = w + 16 * jj;  // wave-uniform
      char* dst = (c < 32) ? (RA + c * 1024)
                : (c < 64) ? (RB + (c - 32) * 1024)
                           : (RA + 32768 + (c - 64) * 1024);
      gld16(wsc + c * 1024 + lane * 16, dst);
    }
  } else {
    stage_w32(Wk, RA, tid);
    stage_w32(Wq, RB, tid);
    stage_w32(Wv, RA + 32768, tid);
  }

  // ---- S row-fragments for pair rows (both subs identical) ----
  bf16x8 sfrag[8];
  {
    const float* srow = S + sbase + (size_t)(32 * p + ml) * 128;
    #pragma unroll
    for (int kk = 0; kk < 8; ++kk) {
      float4 a = *reinterpret_cast<const float4*>(srow + 16 * kk + 8 * hi);
      float4 b = *reinterpret_cast<const float4*>(srow + 16 * kk + 8 * hi + 4);
      bf16x8 f;
      f[0] = (__bf16)a.x; f[1] = (__bf16)a.y; f[2] = (__bf16)a.z; f[3] = (__bf16)a.w;
      f[4] = (__bf16)b.x; f[5] = (__bf16)b.y; f[6] = (__bf16)b.z; f[7] = (__bf16)b.w;
      sfrag[kk] = f;
    }
  }
  __syncthreads();  // #1: W tiles staged

  // ---- K-proj SWAPPED, full d' (duplicated in pair) -> kfrag regs ----
  bf16x8 kfrag[8];
  {
    f32x16 accK[4];
    #pragma unroll
    for (int t = 0; t < 4; ++t) accK[t] = fzero();
    #pragma unroll
    for (int kk = 0; kk < 8; ++kk) {
      #pragma unroll
      for (int t = 0; t < 4; ++t) {
        bf16x8 wf = *reinterpret_cast<const bf16x8*>(
            RA + swzQ(32 * t + ml, 16 * kk + 8 * hi));
        accK[t] = __builtin_amdgcn_mfma_f32_32x32x16_bf16(wf, sfrag[kk], accK[t], 0, 0, 0);
      }
    }
    #pragma unroll
    for (int t = 0; t < 4; ++t) {
      #pragma unroll
      for (int r = 0; r < 16; ++r) accK[t][r] += bk[32 * t + rowmap(r, hi)];
      kfrag[2 * t]     = mk_frag(accK[t][0], accK[t][1], accK[t][2], accK[t][3],
                                 accK[t][4], accK[t][5], accK[t][6], accK[t][7], lane);
      kfrag[2 * t + 1] = mk_frag(accK[t][8], accK[t][9], accK[t][10], accK[t][11],
                                 accK[t][12], accK[t][13], accK[t][14], accK[t][15], lane);
    }
  }

  // ---- V-proj, own d'-half (t = 2s+tt) ----
  f32x16 accV[2];
  accV[0] = fzero(); accV[1] = fzero();
  #pragma unroll
  for (int kk = 0; kk < 8; ++kk) {
    #pragma unroll
    for (int tt = 0; tt < 2; ++tt) {
      int t = 2 * s + tt;
      bf16x8 wf = *reinterpret_cast<const bf16x8*>(
          RA + 32768 + swzQ(32 * t + ml, 16 * kk + 8 * hi));
      accV[tt] = __builtin_amdgcn_mfma_f32_32x32x16_bf16(sfrag[kk], wf, accV[tt], 0, 0, 0);
    }
  }

  // ---- Q-proj, own d'-half ----
  f32x16 accQ[2];
  accQ[0] = fzero(); accQ[1] = fzero();
  #pragma unroll
  for (int kk = 0; kk < 8; ++kk) {
    #pragma unroll
    for (int tt = 0; tt < 2; ++tt) {
      int t = 2 * s + tt;
      bf16x8 wf = *reinterpret_cast<const bf16x8*>(
          RB + swzQ(32 * t + ml, 16 * kk + 8 * hi));
      accQ[tt] = __builtin_amdgcn_mfma_f32_32x32x16_bf16(sfrag[kk], wf, accQ[tt], 0, 0, 0);
    }
  }
  __syncthreads();  // #2: all W reads done; RA/RB reusable

  // ---- write V^T -> RA, Q rows -> RB ----
  #pragma unroll
  for (int tt = 0; tt < 2; ++tt) {
    int t = 2 * s + tt;
    float bb = bv[32 * t + ml];
    int d = 32 * t + ml;
    #pragma unroll
    for (int q = 0; q < 8; ++q) {
      int k = 32 * p + rowmap(2 * q, hi);  // even; pair (k, k+1)
      *reinterpret_cast<unsigned*>(RA + swzV(d, k)) =
          pack2(accV[tt][2 * q] + bb, accV[tt][2 * q + 1] + bb);
    }
  }
  #pragma unroll
  for (int tt = 0; tt < 2; ++tt) {
    int t = 2 * s + tt;
    float bb = bq[32 * t + ml];
    #pragma unroll
    for (int r = 0; r < 16; ++r)
      *reinterpret_cast<__bf16*>(
          RB + swzQ(32 * p + rowmap(r, hi), 32 * t + ml)) =
          (__bf16)(accQ[tt][r] + bb);
  }
  __syncthreads();  // #3: Q + V^T visible

  // ---- attention, own kt-half (kt = 4s+c): sa -> relu -> ctx^T partial ----
  f32x16 ctx[4];
  #pragma unroll
  for (int m = 0; m < 4; ++m) ctx[m] = fzero();
  const float SC = 0.088388347648318447f;  // 1/sqrt(128)

  #pragma unroll
  for (int c = 0; c < 4; ++c) {
    int kt = 4 * s + c;
    f32x16 sa = fzero();
    __builtin_amdgcn_s_setprio(1);
    #pragma unroll
    for (int kk = 0; kk < 8; ++kk) {
      bf16x8 qf = *reinterpret_cast<const bf16x8*>(
          RB + swzQ(32 * kt + ml, 16 * kk + 8 * hi));
      sa = __builtin_amdgcn_mfma_f32_32x32x16_bf16(qf, kfrag[kk], sa, 0, 0, 0);
    }
    __builtin_amdgcn_s_setprio(0);
    float pv[16];
    #pragma unroll
    for (int r = 0; r < 16; ++r) pv[r] = fmaxf(sa[r] * SC, 0.f);
    bf16x8 pf0 = mk_frag(pv[0], pv[1], pv[2], pv[3], pv[4], pv[5], pv[6], pv[7], lane);
    bf16x8 pf1 = mk_frag(pv[8], pv[9], pv[10], pv[11], pv[12], pv[13], pv[14], pv[15], lane);
    __builtin_amdgcn_s_setprio(1);
    #pragma unroll
    for (int m = 0; m < 4; ++m) {
      bf16x8 vf0 = *reinterpret_cast<const bf16x8*>(
          RA + swzV(32 * m + ml, 32 * kt + 8 * hi));
      ctx[m] = __builtin_amdgcn_mfma_f32_32x32x16_bf16(vf0, pf0, ctx[m], 0, 0, 0);
      bf16x8 vf1 = *reinterpret_cast<const bf16x8*>(
          RA + swzV(32 * m + ml, 32 * kt + 16 + 8 * hi));
      ctx[m] = __builtin_amdgcn_mfma_f32_32x32x16_bf16(vf1, pf1, ctx[m], 0, 0, 0);
    }
    __builtin_amdgcn_s_setprio(0);
  }
  __syncthreads();  // #4: all Q (RB) and V^T (RA) reads done

  // ---- Wo DMA -> RB.lo; pair-wise ctx merge through RA (bf16) ----
  if (WS) {
    #pragma unroll
    for (int jj = 0; jj < 2; ++jj) {
      int c = w + 16 * jj;
      gld16(wsc + 98304 + c * 1024 + lane * 16, RB + c * 1024);
    }
  } else {
    stage_w32(Wo, RB, tid);
  }
  char* XC = RA + p * 8192;  // pair-private exchange region [64 d2][32 j] u32
  if (s == 1) {
    #pragma unroll
    for (int m = 0; m < 4; ++m) {
      #pragma unroll
      for (int q = 0; q < 8; ++q) {
        int d2 = (32 * m + rowmap(2 * q, hi)) >> 1;
        *reinterpret_cast<unsigned*>(XC + d2 * 128 + ml * 4) =
            pack2(ctx[m][2 * q], ctx[m][2 * q + 1]);
      }
    }
  }
  __syncthreads();  // #5: sub1 partials visible; Wo DMA drained
  if (s == 0) {
    #pragma unroll
    for (int m = 0; m < 4; ++m) {
      #pragma unroll
      for (int q = 0; q < 8; ++q) {
        int d2 = (32 * m + rowmap(2 * q, hi)) >> 1;
        unsigned u = *reinterpret_cast<unsigned*>(XC + d2 * 128 + ml * 4);
        ctx[m][2 * q]     += bflo(u);
        ctx[m][2 * q + 1] += bfhi(u);
      }
    }
    #pragma unroll
    for (int m = 0; m < 4; ++m) {
      #pragma unroll
      for (int q = 0; q < 8; ++q) {
        int d2 = (32 * m + rowmap(2 * q, hi)) >> 1;
        *reinterpret_cast<unsigned*>(XC + d2 * 128 + ml * 4) =
            pack2(ctx[m][2 * q], ctx[m][2 * q + 1]);
      }
    }
  }
  __syncthreads();  // #6: merged ctx visible
  if (s == 1) {
    #pragma unroll
    for (int m = 0; m < 4; ++m) {
      #pragma unroll
      for (int q = 0; q < 8; ++q) {
        int d2 = (32 * m + rowmap(2 * q, hi)) >> 1;
        unsigned u = *reinterpret_cast<unsigned*>(XC + d2 * 128 + ml * 4);
        ctx[m][2 * q]     = bflo(u);
        ctx[m][2 * q + 1] = bfhi(u);
      }
    }
  }

  // ---- ctx^T -> A-frags; residual loads (own d'-half) ----
  bf16x8 cf[8];
  #pragma unroll
  for (int m = 0; m < 4; ++m) {
    cf[2 * m]     = mk_frag(ctx[m][0], ctx[m][1], ctx[m][2], ctx[m][3],
                            ctx[m][4], ctx[m][5], ctx[m][6], ctx[m][7], lane);
    cf[2 * m + 1] = mk_frag(ctx[m][8], ctx[m][9], ctx[m][10], ctx[m][11],
                            ctx[m][12], ctx[m][13], ctx[m][14], ctx[m][15], lane);
  }
  float resv[2][16];
  #pragma unroll
  for (int tt = 0; tt < 2; ++tt) {
    #pragma unroll
    for (int r = 0; r < 16; ++r)
      resv[tt][r] = S[sbase + (size_t)(32 * p + rowmap(r, hi)) * 128 +
                      32 * (2 * s + tt) + ml];
  }

  // ---- out-proj, own d'-half ----
  f32x16 oa[2];
  oa[0] = fzero(); oa[1] = fzero();
  #pragma unroll
  for (int kk = 0; kk < 8; ++kk) {
    #pragma unroll
    for (int tt = 0; tt < 2; ++tt) {
      int t = 2 * s + tt;
      bf16x8 wf = *reinterpret_cast<const bf16x8*>(
          RB + swzQ(32 * t + ml, 16 * kk + 8 * hi));
      oa[tt] = __builtin_amdgcn_mfma_f32_32x32x16_bf16(cf[kk], wf, oa[tt], 0, 0, 0);
    }
  }

  // ---- epilogue: +bo, +residual, cross-sub LN reduce, store own half ----
  float gg[2], lbv[2], bov[2];
  #pragma unroll
  for (int tt = 0; tt < 2; ++tt) {
    int t = 2 * s + tt;
    gg[tt]  = lg[32 * t + ml];
    lbv[tt] = lb[32 * t + ml];
    bov[tt] = bo[32 * t + ml];
  }
  float sum[16], ssq[16];
  #pragma unroll
  for (int r = 0; r < 16; ++r) { sum[r] = 0.f; ssq[r] = 0.f; }
  #pragma unroll
  for (int tt = 0; tt < 2; ++tt) {
    #pragma unroll
    for (int r = 0; r < 16; ++r) {
      float x = oa[tt][r] + bov[tt] + resv[tt][r];
      oa[tt][r] = x;
      sum[r] += x;
      ssq[r] += x * x;
    }
  }
  char* SX = RB + 32768;  // sums exchange: [pair][32 row][2 sub] float2
  #pragma unroll
  for (int r = 0; r < 16; ++r) {
    float s_ = sum[r], q_ = ssq[r];
    #pragma unroll
    for (int m = 1; m <= 16; m <<= 1) {
      s_ += __shfl_xor(s_, m);
      q_ += __shfl_xor(q_, m);
    }
    if (ml == 0) {
      float2 v; v.x = s_; v.y = q_;
      *reinterpret_cast<float2*>(SX + p * 512 + rowmap(r, hi) * 16 + s * 8) = v;
    }
  }
  __syncthreads();  // #7: partial sums visible
  #pragma unroll
  for (int r = 0; r < 16; ++r) {
    int row = rowmap(r, hi);
    float2 a = *reinterpret_cast<float2*>(SX + p * 512 + row * 16);
    float2 b = *reinterpret_cast<float2*>(SX + p * 512 + row * 16 + 8);
    float mu = (a.x + b.x) * (1.f / 128.f);
    float var = (a.y + b.y) * (1.f / 128.f) - mu * mu;
    float rs = rsqrtf(var + 1e-5f);
    float* orow = out + sbase + (size_t)(32 * p + row) * 128;
    #pragma unroll
    for (int tt = 0; tt < 2; ++tt)
      orow[32 * (2 * s + tt) + ml] = (oa[tt][r] - mu) * rs * gg[tt] + lbv[tt];
  }
}

extern "C" void kernel_launch(void* const* d_in, const int* in_sizes, int n_in,
                              void* d_out, int out_size, void* d_ws, size_t ws_size,
                              hipStream_t stream) {
  (void)in_sizes; (void)n_in; (void)out_size;
  const float* S  = (const float*)d_in[1];
  const float* Wq = (const float*)d_in[2];
  const float* bq = (const float*)d_in[3];
  const float* Wk = (const float*)d_in[4];
  const float* bk = (const float*)d_in[5];
  const float* Wv = (const float*)d_in[6];
  const float* bv = (const float*)d_in[7];
  const float* Wo = (const float*)d_in[8];
  const float* bo = (const float*)d_in[9];
  const float* lg = (const float*)d_in[10];
  const float* lb = (const float*)d_in[11];
  float* out = (float*)d_out;

  constexpr int SMEM = 131072;  // 128 KiB; 1 block/CU, 16 waves = 4/SIMD
  bool use_ws = (d_ws != nullptr) && (ws_size >= 131072);
  if (use_ws) {
    prep_wt<<<dim3(256), dim3(256), 0, stream>>>(Wk, Wq, Wv, Wo, (__bf16*)d_ws);
    (void)hipFuncSetAttribute(reinterpret_cast<const void*>(&sapd_fused<true>),
                              hipFuncAttributeMaxDynamicSharedMemorySize, SMEM);
    sapd_fused<true><<<dim3(512), dim3(1024), SMEM, stream>>>(
        S, bq, bk, bv, bo, Wq, Wk, Wv, Wo, lg, lb, (const __bf16*)d_ws, out);
  } else {
    (void)hipFuncSetAttribute(reinterpret_cast<const void*>(&sapd_fused<false>),
                              hipFuncAttributeMaxDynamicSharedMemorySize, SMEM);
    sapd_fused<false><<<dim3(512), dim3(1024), SMEM, stream>>>(
        S, bq, bk, bv, bo, Wq, Wk, Wv, Wo, lg, lb, nullptr, out);
  }
}